// Round 2
// baseline (460.645 us; speedup 1.0000x reference)
//
#include <hip/hip_runtime.h>

// KVGather: out[b,p,t,:,:] = kv[b, r_idx[b,p,t], :, :]
// B=4, P2=64, TOPK=16, W2=49, C_KV=512
// Output: 4*64*16*49*512 = 102,760,448 f32 = 411 MB (write-bound).
// kv input: 25.7 MB (read-reuse ~16x, absorbed by L2/L3).

constexpr int B    = 4;
constexpr int P2   = 64;
constexpr int TOPK = 16;
constexpr int W2   = 49;
constexpr int C_KV = 512;
constexpr int REGION = W2 * C_KV;        // 25088 floats per region
constexpr int REGION4 = REGION / 4;      // 6272 float4 per region
constexpr int NBLOCKS = B * P2 * TOPK;   // 4096 (one block per output region)
constexpr int TPB = 256;

// clang ext-vector: accepted by __builtin_nontemporal_store (HIP_vector_type is not)
typedef float floatx4 __attribute__((ext_vector_type(4)));

__global__ __launch_bounds__(TPB) void kvgather_kernel(
    const int* __restrict__ r_idx,   // (B, P2, TOPK) flat
    const float* __restrict__ kv,    // (B, P2, W2, C_KV) flat
    float* __restrict__ out)         // (B, P2, TOPK, W2, C_KV) flat
{
    const int bpt = blockIdx.x;              // ((b*P2)+p)*TOPK + t
    const int b   = bpt >> 10;               // / (P2*TOPK) = /1024
    const int src = r_idx[bpt];              // region index in [0, P2)

    const floatx4* __restrict__ s =
        (const floatx4*)(kv + ((size_t)(b * P2 + src)) * REGION);
    floatx4* __restrict__ d =
        (floatx4*)(out + (size_t)bpt * REGION);

    // 6272 float4 / 256 threads = 24.5 iters; coalesced 16B/lane.
    for (int i = threadIdx.x; i < REGION4; i += TPB) {
        floatx4 v = s[i];                         // cached read (reuse ~16x)
        __builtin_nontemporal_store(v, &d[i]);    // streaming write, no L2 pollution
    }
}

extern "C" void kernel_launch(void* const* d_in, const int* in_sizes, int n_in,
                              void* d_out, int out_size, void* d_ws, size_t ws_size,
                              hipStream_t stream) {
    const int*   r_idx = (const int*)d_in[0];
    const float* kv    = (const float*)d_in[1];
    float*       out   = (float*)d_out;

    kvgather_kernel<<<NBLOCKS, TPB, 0, stream>>>(r_idx, kv, out);
}